// Round 2
// baseline (192.005 us; speedup 1.0000x reference)
//
#include <hip/hip_runtime.h>
#include <hip/hip_bf16.h>
#include <cstdint>

#define B_ROWS 16384
#define NCLS 1000
#define NPAD 1024
#define FDIM 768
#define TEMP_INV 10.0f
#define BCAP 128

typedef float floatx4 __attribute__((ext_vector_type(4)));
typedef short short8 __attribute__((ext_vector_type(8)));
typedef unsigned short ushort8v __attribute__((ext_vector_type(8)));

__device__ inline unsigned short f2bf(float f) {
  unsigned int u = __float_as_uint(f);
  u += 0x7FFFu + ((u >> 16) & 1u);   // round-to-nearest-even
  return (unsigned short)(u >> 16);
}

#define GLDS(gp, lp) __builtin_amdgcn_global_load_lds( \
    (const __attribute__((address_space(1))) void*)(gp), \
    (__attribute__((address_space(3))) void*)(lp), 16, 0, 0)

#define CE_BLOCKS  4096     // 16384/4 rows, 4 rows/block
#define CVT_BLOCKS 6528     // (16384*768 + 1024*768)/8/256
#define GEMM_BLOCKS 256     // 64 rowblks x 4 colblks (256x256 tiles)

// ---------------- cvt + CE fused: both memory-bound, share the machine.
// Blocks 0..4095: CE rows (R6-measured path). Blocks 4096..: fp32->bf16 cvt.
__global__ __launch_bounds__(256) void cvt_ce_kernel(
    const float* __restrict__ features, const float* __restrict__ centers,
    unsigned short* __restrict__ fbf, unsigned short* __restrict__ cbf,
    const int* __restrict__ labels, const float* __restrict__ outputs,
    float* __restrict__ ce_partial, int* __restrict__ bcnt) {
  __shared__ float ared[4];
  const int bid = blockIdx.x;
  const int t = threadIdx.x;

  if (bid < CE_BLOCKS) {
    // ---- CE path: one wave per row, 4 rows/block
    const int cb = bid;
    const int wid = t >> 6;
    const int lane = t & 63;
    const int b = cb * 4 + wid;
    const float* row = outputs + (size_t)b * NCLS;
    const float4* r4 = reinterpret_cast<const float4*>(row);
    float4 v[4];
    float m = -1e30f;
#pragma unroll
    for (int it = 0; it < 4; ++it) {
      int idx = lane + it * 64;
      if (idx < 250) v[it] = r4[idx];
      else { v[it].x = -1e30f; v[it].y = -1e30f; v[it].z = -1e30f; v[it].w = -1e30f; }
      m = fmaxf(m, fmaxf(fmaxf(v[it].x, v[it].y), fmaxf(v[it].z, v[it].w)));
    }
#pragma unroll
    for (int msk = 1; msk < 64; msk <<= 1) m = fmaxf(m, __shfl_xor(m, msk));
    float s = 0.f;
#pragma unroll
    for (int it = 0; it < 4; ++it)
      s += __expf(v[it].x - m) + __expf(v[it].y - m) + __expf(v[it].z - m) + __expf(v[it].w - m);
#pragma unroll
    for (int msk = 1; msk < 64; msk <<= 1) s += __shfl_xor(s, msk);
    if (lane == 0) {
      float lse = m + logf(s);
      ared[wid] = lse - row[labels[b]];
    }
    __syncthreads();
    if (t == 0)
      ce_partial[cb] = ared[0] + ared[1] + ared[2] + ared[3];
    return;
  }

  // ---- cvt path
  const int cvtb = bid - CE_BLOCKS;
  if (cvtb < 4) {                       // zero bucket counters for combine
    int z = cvtb * 256 + t;
    if (z < NCLS) bcnt[z] = 0;
  }
  const int NF8 = B_ROWS * FDIM / 8;
  int i = cvtb * 256 + t;
  float4 v0, v1;
  unsigned short* dst;
  if (i < NF8) {
    const float4* s = reinterpret_cast<const float4*>(features) + (size_t)i * 2;
    v0 = s[0]; v1 = s[1];
    dst = fbf + (size_t)i * 8;
  } else {
    int j = i - NF8;
    if (j * 8 < NCLS * FDIM) {
      const float4* s = reinterpret_cast<const float4*>(centers) + (size_t)j * 2;
      v0 = s[0]; v1 = s[1];
    } else {
      v0.x = v0.y = v0.z = v0.w = 0.f;
      v1 = v0;
    }
    dst = cbf + (size_t)j * 8;
  }
  ushort8v o;
  o[0] = f2bf(v0.x); o[1] = f2bf(v0.y); o[2] = f2bf(v0.z); o[3] = f2bf(v0.w);
  o[4] = f2bf(v1.x); o[5] = f2bf(v1.y); o[6] = f2bf(v1.z); o[7] = f2bf(v1.w);
  *reinterpret_cast<ushort8v*>(dst) = o;
}

// ---------------- GEMM 256x256, BK=32 stages, ring-4 LDS slots,
// counted-vmcnt deep pipeline (8-phase-template derivation):
//   - 8 waves (2M x 4N), per-wave 128x64 C, acc[8][4] of 16x16 frags
//   - stage s: 2 phases x 16 MFMA; per phase 2 global_load_lds (prefetch s+3)
//   - boundary s_waitcnt vmcnt(8) (stages s+2,s+3 in flight), epilogue 4->0
//   - XOR swizzle: 16B slot s' = ((row&1)*4+p) ^ ((row>>1)&7) within 128B line
//     (2-way residual conflict = free); staging pre-swizzles the GLOBAL src,
//     LDS stays linear (GLDS wave-uniform-base legal)
__global__ __launch_bounds__(512, 2) void gemm_stats_kernel(
    const unsigned short* __restrict__ fbf,
    const unsigned short* __restrict__ cbf,
    const int* __restrict__ labels,
    float* __restrict__ pm, float* __restrict__ psv,
    float* __restrict__ ztrue) {
  __shared__ __align__(16) unsigned short As[4][8192];   // 4 x 16 KB
  __shared__ __align__(16) unsigned short Bs[4][8192];   // 4 x 16 KB
  __shared__ int lab[256];
  __shared__ float sm[256][4], ss[256][4];

  const int t = threadIdx.x;
  // XCD-aware swizzle: 256 blocks, 8 XCDs, 32 consecutive logical blocks/XCD
  const int lb = ((blockIdx.x & 7) << 5) | (blockIdx.x >> 3);
  const int rowblk = lb >> 2;          // 0..63
  const int colblk = lb & 3;           // 0..3

  const int w = t >> 6, lane = t & 63;
  const int quad = lane >> 4, l15 = lane & 15;
  const int wm = w >> 2, wn = w & 3;

  if (t < 256) lab[t] = labels[rowblk * 256 + t];

  // ---- staging address precompute: chunk c = j*512 + t
  // line L = c>>3, phys slot sp = c&7, logical sl = sp ^ (L&7),
  // row = 2L + (sl>>2), kpiece p = sl&3 (8 bf16 per piece)
  int c0 = t, c1 = 512 + t;
  int L0 = c0 >> 3, sl0 = (c0 & 7) ^ (L0 & 7);
  int L1 = c1 >> 3, sl1 = (c1 & 7) ^ (L1 & 7);
  int row0 = 2 * L0 + (sl0 >> 2), p0 = sl0 & 3;
  int row1 = 2 * L1 + (sl1 >> 2), p1 = sl1 & 3;
  const unsigned short* ag0 = fbf + (size_t)(rowblk * 256 + row0) * FDIM + p0 * 8;
  const unsigned short* ag1 = fbf + (size_t)(rowblk * 256 + row1) * FDIM + p1 * 8;
  const unsigned short* bg0 = cbf + (size_t)(colblk * 256 + row0) * FDIM + p0 * 8;
  const unsigned short* bg1 = cbf + (size_t)(colblk * 256 + row1) * FDIM + p1 * 8;
  const int awr0 = w * 512;            // (0*512 + w*64)*8 ushorts
  const int awr1 = 4096 + w * 512;     // (1*512 + w*64)*8

  // ---- ds_read address precompute (ushort offsets)
  // A frag rb: row = wm*128 + rb*16 + l15 -> off = aoff + rb*512
  const int sA = (((l15 & 1) << 2) | quad) ^ (l15 >> 1);
  const int aoff = wm * 4096 + (l15 >> 1) * 64 + sA * 8;
  const int boff = wn * 2048 + (l15 >> 1) * 64 + sA * 8;

  floatx4 acc[8][4];
#pragma unroll
  for (int i = 0; i < 8; ++i)
#pragma unroll
    for (int j = 0; j < 4; ++j) acc[i][j] = (floatx4){0.f, 0.f, 0.f, 0.f};

  // ---- prologue: stage 0,1,2 in flight; wait until stage 0 resident
#pragma unroll
  for (int s = 0; s < 3; ++s) {
    GLDS(ag0 + s * 32, &As[s][awr0]);
    GLDS(ag1 + s * 32, &As[s][awr1]);
    GLDS(bg0 + s * 32, &Bs[s][awr0]);
    GLDS(bg1 + s * 32, &Bs[s][awr1]);
  }
  asm volatile("s_waitcnt vmcnt(8) lgkmcnt(0)" ::: "memory");
  __builtin_amdgcn_s_barrier();

  // ---- main loop: 24 stages of BK=32
#pragma unroll
  for (int s = 0; s < 24; ++s) {
    const int slot = s & 3;
    const int q = (s + 3) & 3;
    // ---- phase A: frags rb 0..3 (+ all 4 B frags), issue A(s+3)
    short8 af[4], bf4[4];
#pragma unroll
    for (int rb = 0; rb < 4; ++rb)
      af[rb] = *reinterpret_cast<const short8*>(&As[slot][aoff + rb * 512]);
#pragma unroll
    for (int cb = 0; cb < 4; ++cb)
      bf4[cb] = *reinterpret_cast<const short8*>(&Bs[slot][boff + cb * 512]);
    if (s <= 20) {
      GLDS(ag0 + (s + 3) * 32, &As[q][awr0]);
      GLDS(ag1 + (s + 3) * 32, &As[q][awr1]);
    }
    __builtin_amdgcn_s_barrier();
    asm volatile("s_waitcnt lgkmcnt(0)" ::: "memory");
    __builtin_amdgcn_s_setprio(1);
#pragma unroll
    for (int rb = 0; rb < 4; ++rb)
#pragma unroll
      for (int cb = 0; cb < 4; ++cb)
        acc[rb][cb] = __builtin_amdgcn_mfma_f32_16x16x32_bf16(af[rb], bf4[cb], acc[rb][cb], 0, 0, 0);
    __builtin_amdgcn_s_setprio(0);
    __builtin_amdgcn_s_barrier();
    // ---- phase B: frags rb 4..7, issue B(s+3), boundary vmcnt
    short8 af2[4];
#pragma unroll
    for (int rb = 0; rb < 4; ++rb)
      af2[rb] = *reinterpret_cast<const short8*>(&As[slot][aoff + (rb + 4) * 512]);
    if (s <= 20) {
      GLDS(bg0 + (s + 3) * 32, &Bs[q][awr0]);
      GLDS(bg1 + (s + 3) * 32, &Bs[q][awr1]);
    }
    if (s < 21)       asm volatile("s_waitcnt vmcnt(8)" ::: "memory");
    else if (s == 21) asm volatile("s_waitcnt vmcnt(4)" ::: "memory");
    else if (s == 22) asm volatile("s_waitcnt vmcnt(0)" ::: "memory");
    __builtin_amdgcn_s_barrier();
    asm volatile("s_waitcnt lgkmcnt(0)" ::: "memory");
    __builtin_amdgcn_s_setprio(1);
#pragma unroll
    for (int rb = 0; rb < 4; ++rb)
#pragma unroll
      for (int cb = 0; cb < 4; ++cb)
        acc[rb + 4][cb] = __builtin_amdgcn_mfma_f32_16x16x32_bf16(af2[rb], bf4[cb], acc[rb + 4][cb], 0, 0, 0);
    __builtin_amdgcn_s_setprio(0);
    __builtin_amdgcn_s_barrier();
  }

  // ---- epilogue: z = 10*sims; per-row partials over this block's 256 cols
  const int gcol0 = colblk * 256 + wn * 64;
#pragma unroll
  for (int rb = 0; rb < 8; ++rb) {
#pragma unroll
    for (int r = 0; r < 4; ++r) {
      const int lrow = wm * 128 + rb * 16 + quad * 4 + r;
      float zv[4];
      float m = -1e30f;
#pragma unroll
      for (int cb = 0; cb < 4; ++cb) {
        float z = acc[rb][cb][r] * TEMP_INV;
        int gc = gcol0 + cb * 16 + l15;
        if (gc == lab[lrow]) ztrue[rowblk * 256 + lrow] = z;
        if (gc >= NCLS) z = -1e30f;
        zv[cb] = z;
        m = fmaxf(m, z);
      }
#pragma unroll
      for (int msk = 1; msk < 16; msk <<= 1) m = fmaxf(m, __shfl_xor(m, msk));
      float sum = 0.f;
#pragma unroll
      for (int cb = 0; cb < 4; ++cb) sum += __expf(zv[cb] - m);
#pragma unroll
      for (int msk = 1; msk < 16; msk <<= 1) sum += __shfl_xor(sum, msk);
      if (l15 == 0) { sm[lrow][wn] = m; ss[lrow][wn] = sum; }
    }
  }
  __syncthreads();
  if (t < 256) {
    float m0 = sm[t][0], m1 = sm[t][1], m2 = sm[t][2], m3 = sm[t][3];
    float mn = fmaxf(fmaxf(m0, m1), fmaxf(m2, m3));
    float S = ss[t][0] * __expf(m0 - mn) + ss[t][1] * __expf(m1 - mn)
            + ss[t][2] * __expf(m2 - mn) + ss[t][3] * __expf(m3 - mn);
    int grow = rowblk * 256 + t;
    pm[colblk * B_ROWS + grow] = mn;
    psv[colblk * B_ROWS + grow] = S;
  }
}

// ---------------- combine: merge 4 partials -> p, SDC partials, class buckets
__global__ __launch_bounds__(256) void combine_kernel(
    const float* __restrict__ pm, const float* __restrict__ psv,
    const float* __restrict__ ztrue, const int* __restrict__ labels,
    int* __restrict__ bcnt, int* __restrict__ bidx, float* __restrict__ bp,
    float* __restrict__ sdc_partial) {
  __shared__ float wred[4];
  const int b = blockIdx.x * 256 + threadIdx.x;
  float mj[4];
  float M = -1e30f;
#pragma unroll
  for (int j = 0; j < 4; ++j) { mj[j] = pm[j * B_ROWS + b]; M = fmaxf(M, mj[j]); }
  float S = 0.f;
#pragma unroll
  for (int j = 0; j < 4; ++j) S += psv[j * B_ROWS + b] * __expf(mj[j] - M);
  float p = __expf(ztrue[b] - M) / S;
  int lb = labels[b];
  int slot = atomicAdd(&bcnt[lb], 1);
  if (slot < BCAP) { bidx[lb * BCAP + slot] = b; bp[lb * BCAP + slot] = p; }
  float v = -logf(p + 1e-8f);
#pragma unroll
  for (int msk = 1; msk < 64; msk <<= 1) v += __shfl_xor(v, msk);
  if ((threadIdx.x & 63) == 0) wred[threadIdx.x >> 6] = v;
  __syncthreads();
  if (threadIdx.x == 0)
    sdc_partial[blockIdx.x] = wred[0] + wred[1] + wred[2] + wred[3];
}

// ---------------- mstep: one block per class, direct bucket gather.
__global__ __launch_bounds__(256) void mstep_kernel(
    const float* __restrict__ features,
    const float* __restrict__ centers,
    const int* __restrict__ bcnt, const int* __restrict__ bidx,
    const float* __restrict__ bp,
    const float* __restrict__ ce_partial, const float* __restrict__ sdc_partial,
    float* __restrict__ out_loss, float* __restrict__ out_centers) {
  const int c = blockIdx.x;
  const int t = threadIdx.x;
  if (c == 0) {
    __shared__ float red[256];
    float s = 0.f;
    for (int i = t; i < CE_BLOCKS; i += 256) s += ce_partial[i];
    float s2 = 0.f;
    for (int i = t; i < 64; i += 256) s2 += sdc_partial[i];
    red[t] = s + 0.1f * s2;
    __syncthreads();
    for (int off = 128; off > 0; off >>= 1) {
      if (t < off) red[t] += red[t + off];
      __syncthreads();
    }
    if (t == 0) out_loss[0] = red[0] * (1.0f / 16384.0f);
  }
  int n = bcnt[c];
  if (n > BCAP) n = BCAP;
  float a0 = 0.f, a1 = 0.f, a2 = 0.f, ws = 0.f;
  int j = 0;
  for (; j + 2 <= n; j += 2) {
    int b0 = bidx[c * BCAP + j], b1 = bidx[c * BCAP + j + 1];
    float p0 = bp[c * BCAP + j], p1 = bp[c * BCAP + j + 1];
    const float* f0 = features + (size_t)b0 * FDIM;
    const float* f1 = features + (size_t)b1 * FDIM;
    float x00 = f0[t], x01 = f0[t + 256], x02 = f0[t + 512];
    float x10 = f1[t], x11 = f1[t + 256], x12 = f1[t + 512];
    a0 += p0 * x00 + p1 * x10;
    a1 += p0 * x01 + p1 * x11;
    a2 += p0 * x02 + p1 * x12;
    ws += p0 + p1;
  }
  if (j < n) {
    int b0 = bidx[c * BCAP + j];
    float p0 = bp[c * BCAP + j];
    const float* f0 = features + (size_t)b0 * FDIM;
    a0 += p0 * f0[t]; a1 += p0 * f0[t + 256]; a2 += p0 * f0[t + 512];
    ws += p0;
  }
  const float* crow = centers + (size_t)c * FDIM;
  float c0 = crow[t], c1 = crow[t + 256], c2 = crow[t + 512];
  size_t o = (size_t)c * FDIM + t;
  if (ws > 0.f) {
    float inv = 0.1f / (ws + 1e-8f);
    out_centers[o]       = 0.9f * c0 + a0 * inv;
    out_centers[o + 256] = 0.9f * c1 + a1 * inv;
    out_centers[o + 512] = 0.9f * c2 + a2 * inv;
  } else {
    out_centers[o]       = c0;
    out_centers[o + 256] = c1;
    out_centers[o + 512] = c2;
  }
}

extern "C" void kernel_launch(void* const* d_in, const int* in_sizes, int n_in,
                              void* d_out, int out_size, void* d_ws, size_t ws_size,
                              hipStream_t stream) {
  const float* outputs  = (const float*)d_in[0];
  const int*   labels   = (const int*)d_in[1];
  const float* features = (const float*)d_in[2];
  const float* centers  = (const float*)d_in[3];
  float* out = (float*)d_out;

  char* ws = (char*)d_ws;
  float* ztrue       = (float*)(ws);                          // 64 KB
  float* ce_partial  = (float*)(ws + (64 << 10));             // 16 KB
  float* sdc_partial = (float*)(ws + (80 << 10));             // 256 B
  int*   bcnt        = (int*)(ws + (84 << 10));               // 4 KB
  float* pm          = (float*)(ws + (88 << 10));             // 256 KB used
  float* psv         = (float*)(ws + (600 << 10));            // 256 KB used
  unsigned short* cbf = (unsigned short*)(ws + (1112 << 10)); // 1.5 MB
  unsigned short* fbf = (unsigned short*)(ws + (2648 << 10)); // 24 MB
  // buckets overlay fbf (dead after gemm; written in combine, read in mstep)
  int*   bidx        = (int*)(ws + (2648 << 10));             // 512 KB
  float* bp          = (float*)(ws + (3160 << 10));           // 512 KB

  cvt_ce_kernel<<<CE_BLOCKS + CVT_BLOCKS, 256, 0, stream>>>(
      features, centers, fbf, cbf, labels, outputs, ce_partial, bcnt);
  gemm_stats_kernel<<<GEMM_BLOCKS, 512, 0, stream>>>(
      fbf, cbf, labels, pm, psv, ztrue);
  combine_kernel<<<B_ROWS / 256, 256, 0, stream>>>(pm, psv, ztrue, labels,
                                                   bcnt, bidx, bp, sdc_partial);
  mstep_kernel<<<NCLS, 256, 0, stream>>>(features, centers, bcnt, bidx, bp,
                                         ce_partial, sdc_partial, out, out + 1);
}